// Round 11
// baseline (641.075 us; speedup 1.0000x reference)
//
#include <hip/hip_runtime.h>
#include <math.h>

// PointPWC multi-scale loss. B=2, scales N={8192,4096,2048,1024}.
// Inputs (B,3,N) fp32 channel-major. Output: single fp32 scalar.
//
// R19 = R18 with k_epi FUSED into k_work behind a software grid barrier.
// Evidence: total - k_work = 50.7us (R18) for two trivial kernels ->
// ~10-15us fixed dispatch floor each (documented launch-overhead
// plateau) + latency-exposed runs. All 1024 k_work blocks are exactly
// co-resident (4/CU x 256, launch_bounds(512,8), VGPR 32, LDS 23KB), so
// a device-scope arrive/spin barrier (release fetch_add + acquire load,
// +threadfence writeback/invalidate for cross-XCD L2) lets the epilogue
// run in-kernel: blocks 0..59 x 512 items (scale boundaries divisible by
// 512 -> alpha wave-uniform), LDS reduce -> 60 atomicAdds. k_init stays:
// its kernel boundary keeps warp[] (read via K$ s_load) and queue/bar
// init safe. k_work task body unchanged from R14/R18 (239us, keys
// bit-identical).

#define UNIT 1024
#define NTOT 15360
#define MASKC 0xFFFFE000u
#define NTASK 2380u   // 340 A + 340 B + 340 C + 1360 D-micro
#define NBLK 1024u

typedef unsigned int uint;
typedef __attribute__((ext_vector_type(16))) float f16v;

struct Params {
  const float* pc1[4];
  const float* pc2[4];
  const float* fl[4];
  float4* cv2;   // [B][NTOT]
  float4* cvw;   // [B][NTOT]
  float* keys;   // [5][B*NTOT] packed top-5 keys (pass C)
  uint* d2u;     // [B*NTOT] partial mins (pass D)
  uint* cnt;     // [0]=task queue, [1]=grid barrier
  float* warp;   // per-scale [B][3][N] warped p1 (= p1+fl)
  float* out;
};

// ---------- helpers ----------

__device__ __forceinline__ float wave_sum(float v) {
  #pragma unroll
  for (int o = 32; o; o >>= 1) v += __shfl_down(v, o, 64);
  return v;
}

template <int K>
__device__ __forceinline__ void key_insert(float (&kd)[K], float kf) {
  #pragma unroll
  for (int m = K - 1; m >= 1; --m)
    kd[m] = __builtin_amdgcn_fmed3f(kf, kd[m - 1], kd[m]);
  kd[0] = fminf(kd[0], kf);
}

template <int K>
__device__ __forceinline__ void merge_pair(float (&a)[K], const float (&b)[K]) {
  #pragma unroll
  for (int m = 0; m < K; ++m) key_insert<K>(a, b[m]);
}

__device__ __forceinline__ float pack_key_u(float d, uint iw) {
  return __uint_as_float((__float_as_uint(d) & MASKC) | iw);
}

// Wave-uniform broadcast of 16 candidates (3 planes, 12B/cand) into
// SGPRs. Loads + waitcnt fused in ONE asm block (SMEM completes
// out-of-order; only lgkmcnt(0) is safe). Pointers block-uniform.
__device__ __forceinline__ void sload3x16(const float* px, const float* py,
                                          const float* pz, int boff,
                                          f16v& x, f16v& y, f16v& z) {
  asm volatile(
      "s_load_dwordx16 %0, %3, %6\n\t"
      "s_load_dwordx16 %1, %4, %6\n\t"
      "s_load_dwordx16 %2, %5, %6\n\t"
      "s_waitcnt lgkmcnt(0)"
      : "=&s"(x), "=&s"(y), "=&s"(z)
      : "s"(px), "s"(py), "s"(pz), "s"(boff));
}

// Top-K scan over [lo, lo+UNIT); candidates from SGPRs. Two chains.
template <int K>
__device__ void scan_k(const float* px, const float* py, const float* pz,
                       int lo, float ax, float ay, float az,
                       float (&a)[K], float (&b)[K]) {
  #pragma unroll 1
  for (int c0 = 0; c0 < UNIT; c0 += 16) {
    f16v xs, ys, zs;
    sload3x16(px, py, pz, (lo + c0) * 4, xs, ys, zs);
    #pragma unroll
    for (int t = 0; t < 16; t += 2) {
      float dxa = xs[t] - ax, dya = ys[t] - ay, dza = zs[t] - az;
      float dA = fmaf(dxa, dxa, fmaf(dya, dya, dza * dza));
      float dxb = xs[t + 1] - ax, dyb = ys[t + 1] - ay, dzb = zs[t + 1] - az;
      float dB = fmaf(dxb, dxb, fmaf(dyb, dyb, dzb * dzb));
      key_insert<K>(a, pack_key_u(dA, (uint)(lo + c0 + t)));
      key_insert<K>(b, pack_key_u(dB, (uint)(lo + c0 + t + 1)));
    }
  }
}

// Min-only scan over [lo, lo+len): candidates from SGPRs (pass D uses
// precomputed warp -> 7 VALU/candidate).
__device__ void scan_m(const float* px, const float* py, const float* pz,
                       int lo, int len, float ax, float ay, float az,
                       float& a0, float& b0) {
  #pragma unroll 1
  for (int c0 = 0; c0 < len; c0 += 16) {
    f16v xs, ys, zs;
    sload3x16(px, py, pz, (lo + c0) * 4, xs, ys, zs);
    #pragma unroll
    for (int t = 0; t < 16; t += 2) {
      float dxa = xs[t] - ax, dya = ys[t] - ay, dza = zs[t] - az;
      float dA = fmaf(dxa, dxa, fmaf(dya, dya, dza * dza));
      float dxb = xs[t + 1] - ax, dyb = ys[t + 1] - ay, dzb = zs[t + 1] - az;
      float dB = fmaf(dxb, dxb, fmaf(dyb, dyb, dzb * dzb));
      a0 = fminf(a0, dA);
      b0 = fminf(b0, dB);
    }
  }
}

// r in [0,340) -> scale s, batch b, query-group base i0, candidate lo.
// Only i0/lo depend on wv; s,b are block-uniform.
__device__ __forceinline__ void decode(int r, int wv, int& s, int& b,
                                       int& i0, int& lo, int& N, int& cpw,
                                       int& off, float& alpha) {
  int rr;
  if (r < 256)      { s = 0; rr = r; }
  else if (r < 320) { s = 1; rr = r - 256; }
  else if (r < 336) { s = 2; rr = r - 320; }
  else              { s = 3; rr = r - 336; }
  N = 8192 >> s;
  cpw = 8 >> s;
  int perb = 128 >> (2 * s);
  b = rr >> (7 - 2 * s);
  int chunk = rr & (perb - 1);
  int qg = (chunk << s) + (wv >> (3 - s));
  i0 = qg << 6;
  lo = (wv & (cpw - 1)) << 10;
  off = 16384 - (16384 >> s);
  alpha = 0.02f * (float)(1 << s);
}

// Stage per-thread list; group leader (wave with cr==0) merges its
// qgroup's cpw lists. Returns true for leader threads.
template <int K>
__device__ __forceinline__ bool merge_group(float (&a)[K], float* sm,
                                            int tid, int cpw) {
  const int STR = K | 1;   // odd stride: 2-way bank aliasing only (free)
  int q = tid & 63, wv = tid >> 6;
  #pragma unroll
  for (int m = 0; m < K; ++m) sm[(wv * 64 + q) * STR + m] = a[m];
  __syncthreads();
  if (wv & (cpw - 1)) return false;
  for (int w = wv + 1; w < wv + cpw; ++w)
    #pragma unroll
    for (int m = 0; m < K; ++m)
      key_insert<K>(a, sm[(w * 64 + q) * STR + m]);
  return true;
}

// ---------- kernels ----------

// Init scalars/d2u/barrier AND precompute warp = p1+fl (flat per scale;
// same rounding as the p1[j]+fl[j] it replaces -> bit-identical).
// This kernel's boundary also makes warp[] (read via K$ s_load in
// k_work) and queue/bar init safely visible.
__global__ __launch_bounds__(256) void k_init(Params P) {
  int t = blockIdx.x * 256 + threadIdx.x;
  if (t == 0) { P.out[0] = 0.f; P.cnt[0] = NBLK; P.cnt[1] = 0u; }
  if (t < 2 * NTOT) P.d2u[t] = 0x7F7FFFFFu;         // FLT_MAX bits
  int s, r;
  if (t < 49152)      { s = 0; r = t; }
  else if (t < 73728) { s = 1; r = t - 49152; }
  else if (t < 86016) { s = 2; r = t - 73728; }
  else if (t < 92160) { s = 3; r = t - 86016; }
  else return;
  int base6 = (s == 0) ? 0 : (s == 1) ? 49152 : (s == 2) ? 73728 : 86016;
  P.warp[base6 + r] = P.pc1[s][r] + P.fl[s][r];
}

// Persistent blocks; task t: [0,340) A, [340,680) B, [680,1020) C,
// [1020,2380) D-micro. Then: grid barrier + fused epilogue.
__global__ __launch_bounds__(512, 8) void k_work(Params P) {
  __shared__ float sm[8 * 64 * 11];   // 22.5 KB merge staging
  __shared__ uint ts;
  int tid = threadIdx.x, q = tid & 63, wv = tid >> 6;

  uint t = blockIdx.x;                // static first task, no pop burst
  while (t < NTASK) {
    if (t < 1020u) {
      int pass = (int)t / 340, r = (int)t % 340;
      int s, b, i0, lo, N, cpw, off; float alpha;
      decode(r, wv, s, b, i0, lo, N, cpw, off, alpha);
      int i = i0 + q;
      int lo_u = __builtin_amdgcn_readfirstlane(lo);

      if (pass == 0) {            // A: p2 self top-10 -> cv2
        const float* p2 = P.pc2[s] + b * 3 * N;
        float ax = p2[i], ay = p2[N + i], az = p2[2 * N + i];
        float a[10], bb[10];
        #pragma unroll
        for (int m = 0; m < 10; ++m) { a[m] = 3.0e38f; bb[m] = 3.0e38f; }
        scan_k<10>(p2, p2 + N, p2 + 2 * N, lo_u, ax, ay, az, a, bb);
        merge_pair<10>(a, bb);
        if (merge_group<10>(a, sm, tid, cpw)) {
          float sx = 0.f, sy = 0.f, sz = 0.f;
          #pragma unroll
          for (int m = 0; m < 10; ++m) {
            int j = (int)(__float_as_uint(a[m]) & 0x1FFFu);
            sx += p2[j]; sy += p2[N + j]; sz += p2[2 * N + j];
          }
          const float inv9 = 1.f / 9.f;
          P.cv2[b * NTOT + off + i] = make_float4((sx - 10.f * ax) * inv9,
                                                  (sy - 10.f * ay) * inv9,
                                                  (sz - 10.f * az) * inv9,
                                                  0.f);
        }
      } else if (pass == 1) {     // B: p1 self top-10 -> cvw + smooth
        const float* p1 = P.pc1[s] + b * 3 * N;
        const float* fl = P.fl[s] + b * 3 * N;
        float ax = p1[i], ay = p1[N + i], az = p1[2 * N + i];
        float a[10], bb[10];
        #pragma unroll
        for (int m = 0; m < 10; ++m) { a[m] = 3.0e38f; bb[m] = 3.0e38f; }
        scan_k<10>(p1, p1 + N, p1 + 2 * N, lo_u, ax, ay, az, a, bb);
        merge_pair<10>(a, bb);
        if (merge_group<10>(a, sm, tid, cpw)) {
          float fix = fl[i], fiy = fl[N + i], fiz = fl[2 * N + i];
          float wix = ax + fix, wiy = ay + fiy, wiz = az + fiz;
          float sx = 0.f, sy = 0.f, sz = 0.f, smooth = 0.f;
          float dmax = -1.f, worst = 0.f;
          #pragma unroll
          for (int m = 0; m < 10; ++m) {
            int j = (int)(__float_as_uint(a[m]) & 0x1FFFu);
            float px = p1[j], py = p1[N + j], pz = p1[2 * N + j];
            float flx = fl[j], fly = fl[N + j], flz = fl[2 * N + j];
            sx += px + flx; sy += py + fly; sz += pz + flz;
            float ddx = px - ax, ddy = py - ay, ddz = pz - az;
            float d = fmaf(ddx, ddx, fmaf(ddy, ddy, ddz * ddz));  // exact
            float gx = flx - fix, gy = fly - fiy, gz = flz - fiz;
            float term = sqrtf(fmaf(gx, gx, fmaf(gy, gy, gz * gz)));
            smooth += term;
            if (d > dmax) { dmax = d; worst = term; }  // drop farthest (k9)
          }
          smooth -= worst;
          const float inv9 = 1.f / 9.f;
          P.cvw[b * NTOT + off + i] = make_float4((sx - 10.f * wix) * inv9,
                                                  (sy - 10.f * wiy) * inv9,
                                                  (sz - 10.f * wiz) * inv9,
                                                  0.f);
          float ssum = wave_sum(smooth * (1.f / 8.f));
          if (q == 0) atomicAdd(P.out, alpha * 0.5f * ssum);
        }
      } else {                    // C: warp -> p2 top-5 -> packed keys
        int base6 = (s == 0) ? 0 : (s == 1) ? 49152 : (s == 2) ? 73728
                                                               : 86016;
        const float* wq = P.warp + base6 + b * 3 * N;
        const float* p2 = P.pc2[s] + b * 3 * N;
        float ax = wq[i], ay = wq[N + i], az = wq[2 * N + i];  // == p1+fl
        float a[5], bb[5];
        #pragma unroll
        for (int m = 0; m < 5; ++m) { a[m] = 3.0e38f; bb[m] = 3.0e38f; }
        scan_k<5>(p2, p2 + N, p2 + 2 * N, lo_u, ax, ay, az, a, bb);
        merge_pair<5>(a, bb);
        if (merge_group<5>(a, sm, tid, cpw)) {
          #pragma unroll
          for (int m = 0; m < 5; ++m)
            P.keys[m * (2 * NTOT) + b * NTOT + off + i] = a[m];
        }
      }
    } else {                      // D-micro: p2 -> warp min, atomicMin
      int dm = (int)(t - 1020u);
      int s, tb;
      if (dm < 1024)      { s = 0; tb = dm; }
      else if (dm < 1280) { s = 1; tb = dm - 1024; }
      else if (dm < 1344) { s = 2; tb = dm - 1280; }
      else                { s = 3; tb = dm - 1344; }
      int N = 8192 >> s;
      int tpb = 512 >> (2 * s);            // tasks per batch
      int b = tb >> (9 - 2 * s);
      int ti = tb & (tpb - 1);
      int u = ti * 8 + wv;                 // wave-unit within batch
      int rpq = 32 >> s;                   // 256-ranges per qgroup
      int qg = u >> (5 - s);
      int rg = u & (rpq - 1);
      int i = qg * 64 + q, lo = rg * 256;
      int off = 16384 - (16384 >> s);
      int base6 = (s == 0) ? 0 : (s == 1) ? 49152 : (s == 2) ? 73728
                                                             : 86016;
      const float* wc = P.warp + base6 + b * 3 * N;  // block-uniform
      const float* p2 = P.pc2[s] + b * 3 * N;
      float ax = p2[i], ay = p2[N + i], az = p2[2 * N + i];
      float a0 = 3.0e38f, b0 = 3.0e38f;
      int lo_u = __builtin_amdgcn_readfirstlane(lo);
      scan_m(wc, wc + N, wc + 2 * N, lo_u, 256, ax, ay, az, a0, b0);
      atomicMin(P.d2u + b * NTOT + off + i, __float_as_uint(fminf(a0, b0)));
    }
    __syncthreads();              // sm + ts reuse safety
    if (tid == 0) ts = atomicAdd(P.cnt, 1u);
    __syncthreads();
    t = ts;
  }

  // ---- software grid barrier (all 1024 blocks co-resident) ----
  // Prior stores are in L2 (loop's __syncthreads drained vmcnt).
  // Release: writeback + arrive. Acquire: spin + invalidate.
  if (tid == 0) {
    __threadfence();   // agent fence: write back dirty L2 (cross-XCD)
    __hip_atomic_fetch_add(P.cnt + 1, 1u, __ATOMIC_ACQ_REL,
                           __HIP_MEMORY_SCOPE_AGENT);
    uint v;
    do {
      v = __hip_atomic_load(P.cnt + 1, __ATOMIC_ACQUIRE,
                            __HIP_MEMORY_SCOPE_AGENT);
      if (v < NBLK) __builtin_amdgcn_s_sleep(2);
    } while (v < NBLK);
    __threadfence();   // invalidate stale cache lines before reads
  }
  __syncthreads();

  // ---- fused epilogue (ex-k_epi): blocks 0..59 x 512 items ----
  // Scale boundaries (8192/12288/14336/15360 and +NTOT) are all
  // multiples of 512 -> s,alpha wave-uniform within each wave.
  if (blockIdx.x >= 60u) return;
  int it = (int)blockIdx.x * 512 + tid;     // [0, 2*NTOT)
  int b = it >= NTOT;
  int r = it - b * NTOT;
  int s, i;
  if (r < 8192)       { s = 0; i = r; }
  else if (r < 12288) { s = 1; i = r - 8192; }
  else if (r < 14336) { s = 2; i = r - 12288; }
  else                { s = 3; i = r - 14336; }
  int N = 8192 >> s;
  int off = 16384 - (16384 >> s);
  float alpha = 0.02f * (float)(1 << s);
  const float* p1 = P.pc1[s] + b * 3 * N;
  const float* fl = P.fl[s] + b * 3 * N;
  const float* p2 = P.pc2[s] + b * 3 * N;
  float ax = p1[i] + fl[i], ay = p1[N + i] + fl[N + i],
        az = p1[2 * N + i] + fl[2 * N + i];
  float dist1 = 3.0e38f, wsum = 0.f, ix = 0.f, iy = 0.f, iz = 0.f;
  #pragma unroll
  for (int m = 0; m < 5; ++m) {
    uint key = __float_as_uint(P.keys[m * (2 * NTOT) + b * NTOT + off + i]);
    int j = (int)(key & 0x1FFFu);
    float px = p2[j], py = p2[N + j], pz = p2[2 * N + j];
    float ddx = px - ax, ddy = py - ay, ddz = pz - az;
    float d = fmaf(ddx, ddx, fmaf(ddy, ddy, ddz * ddz));  // exact
    dist1 = fminf(dist1, d);
    float w = 1.f / (d + 1e-8f);
    wsum += w;
    float4 cv = P.cv2[b * NTOT + off + j];
    ix += w * cv.x; iy += w * cv.y; iz += w * cv.z;
  }
  float inv = 1.f / wsum;
  ix *= inv; iy *= inv; iz *= inv;
  float4 cw = P.cvw[b * NTOT + off + i];
  float ex = ix - cw.x, ey = iy - cw.y, ez = iz - cw.z;
  float curv = fmaf(ex, ex, fmaf(ey, ey, ez * ez));
  // per-item weighting before the reduce (safe even at boundaries)
  float v = alpha * 0.5f * (dist1 + 0.3f * curv)
          + alpha * 0.5f * __uint_as_float(P.d2u[it]);
  v = wave_sum(v);
  if (q == 0) sm[wv] = v;
  __syncthreads();
  if (tid == 0) {
    float tot = 0.f;
    #pragma unroll
    for (int m = 0; m < 8; ++m) tot += sm[m];
    atomicAdd(P.out, tot);       // 60 total
  }
}

extern "C" void kernel_launch(void* const* d_in, const int* in_sizes, int n_in,
                              void* d_out, int out_size, void* d_ws,
                              size_t ws_size, hipStream_t stream) {
  Params P;
  for (int s = 0; s < 4; ++s) {
    P.pc1[s] = (const float*)d_in[s];
    P.pc2[s] = (const float*)d_in[4 + s];
    P.fl[s]  = (const float*)d_in[8 + s];
  }
  char* ws = (char*)d_ws;
  P.cv2  = (float4*)ws;                    // 491520 B
  P.cvw  = (float4*)(ws + 491520);         // 491520 B
  P.keys = (float*)(ws + 983040);          // 614400 B
  P.d2u  = (uint*)(ws + 1597440);          // 122880 B
  P.cnt  = (uint*)(ws + 1720320);          // 64 B
  P.warp = (float*)(ws + 1720384);         // 368640 B (total 2089024)
  P.out  = (float*)d_out;

  k_init<<<dim3(360), dim3(256), 0, stream>>>(P);
  k_work<<<dim3(NBLK), dim3(512), 0, stream>>>(P);
}

// Round 13
// 303.778 us; speedup vs baseline: 2.1103x; 2.1103x over previous
//
#include <hip/hip_runtime.h>
#include <math.h>

// PointPWC multi-scale loss. B=2, scales N={8192,4096,2048,1024}.
// Inputs (B,3,N) fp32 channel-major. Output: single fp32 scalar.
//
// R21 = R20 resubmitted verbatim (R12 bench was an infra flake:
// "container failed twice", no compile error, no profile; kernel-side
// hang ruled out: queue strictly increasing, barriers uniform, decode
// bounds checked, no new asm/atomics).
//
// R20 rationale: R18's 50.7us gap = k_init + k_epi + boundaries.
//  1. k_init DELETED: pass C computes query p1[i]+fl[i] per-lane (R10
//     exact code, bit-identical); pass D candidates via sload6 x8
//     broadcast (R10's proven scan_w, bit-identical math).
//  2. d2u/atomicMin DELETED: pass D = self-contained block tasks, 64
//     queries x full N, 8 waves x N/8 cands + LDS merge_group<1> (R10's
//     pass-2 path) -> wave_sum -> 1 atomicAdd. 480 tasks (0.3-2.1us)
//     stay ideal drain fillers. No partials, no init, no epilogue-D.
//  3. out/cnt zeroed by 1-thread k_zero (R8 pattern, featherweight).
//  4. k_epi: C-epilogue only + R18 block-level atomic reduction.
// k_work A/B/C bodies unchanged from R14/R18 (239us, keys bit-identical).

#define UNIT 1024
#define NTOT 15360
#define MASKC 0xFFFFE000u
#define NTASK 1500u   // 340 A + 340 B + 340 C + 480 D-block
#define NBLK 1024u

typedef unsigned int uint;
typedef __attribute__((ext_vector_type(8))) float f8;
typedef __attribute__((ext_vector_type(16))) float f16v;

struct Params {
  const float* pc1[4];
  const float* pc2[4];
  const float* fl[4];
  float4* cv2;   // [B][NTOT]
  float4* cvw;   // [B][NTOT]
  float* keys;   // [5][B*NTOT] packed top-5 keys (pass C)
  uint* cnt;     // task queue counter (starts 0; pops add NBLK)
  float* out;
};

// ---------- helpers ----------

__device__ __forceinline__ float wave_sum(float v) {
  #pragma unroll
  for (int o = 32; o; o >>= 1) v += __shfl_down(v, o, 64);
  return v;
}

template <int K>
__device__ __forceinline__ void key_insert(float (&kd)[K], float kf) {
  #pragma unroll
  for (int m = K - 1; m >= 1; --m)
    kd[m] = __builtin_amdgcn_fmed3f(kf, kd[m - 1], kd[m]);
  kd[0] = fminf(kd[0], kf);
}

template <int K>
__device__ __forceinline__ void merge_pair(float (&a)[K], const float (&b)[K]) {
  #pragma unroll
  for (int m = 0; m < K; ++m) key_insert<K>(a, b[m]);
}

__device__ __forceinline__ float pack_key_u(float d, uint iw) {
  return __uint_as_float((__float_as_uint(d) & MASKC) | iw);
}

// Wave-uniform broadcast of 16 candidates (3 planes, 12B/cand) into
// SGPRs. Loads + waitcnt fused in ONE asm block (SMEM completes
// out-of-order; only lgkmcnt(0) is safe). Pointers block-uniform.
__device__ __forceinline__ void sload3x16(const float* px, const float* py,
                                          const float* pz, int boff,
                                          f16v& x, f16v& y, f16v& z) {
  asm volatile(
      "s_load_dwordx16 %0, %3, %6\n\t"
      "s_load_dwordx16 %1, %4, %6\n\t"
      "s_load_dwordx16 %2, %5, %6\n\t"
      "s_waitcnt lgkmcnt(0)"
      : "=&s"(x), "=&s"(y), "=&s"(z)
      : "s"(px), "s"(py), "s"(pz), "s"(boff));
}

// 6-plane x8 broadcast for pass D (p1 + fl streams; R10-proven).
__device__ __forceinline__ void sload6(const float* px, const float* py,
                                       const float* pz, const float* fx,
                                       const float* fy, const float* fz,
                                       int boff, f8& x, f8& y, f8& z,
                                       f8& u, f8& v, f8& w) {
  asm volatile(
      "s_load_dwordx8 %0, %6, %12\n\t"
      "s_load_dwordx8 %1, %7, %12\n\t"
      "s_load_dwordx8 %2, %8, %12\n\t"
      "s_load_dwordx8 %3, %9, %12\n\t"
      "s_load_dwordx8 %4, %10, %12\n\t"
      "s_load_dwordx8 %5, %11, %12\n\t"
      "s_waitcnt lgkmcnt(0)"
      : "=&s"(x), "=&s"(y), "=&s"(z), "=&s"(u), "=&s"(v), "=&s"(w)
      : "s"(px), "s"(py), "s"(pz), "s"(fx), "s"(fy), "s"(fz), "s"(boff));
}

// Top-K scan over [lo, lo+UNIT); candidates from SGPRs. Two chains.
template <int K>
__device__ void scan_k(const float* px, const float* py, const float* pz,
                       int lo, float ax, float ay, float az,
                       float (&a)[K], float (&b)[K]) {
  #pragma unroll 1
  for (int c0 = 0; c0 < UNIT; c0 += 16) {
    f16v xs, ys, zs;
    sload3x16(px, py, pz, (lo + c0) * 4, xs, ys, zs);
    #pragma unroll
    for (int t = 0; t < 16; t += 2) {
      float dxa = xs[t] - ax, dya = ys[t] - ay, dza = zs[t] - az;
      float dA = fmaf(dxa, dxa, fmaf(dya, dya, dza * dza));
      float dxb = xs[t + 1] - ax, dyb = ys[t + 1] - ay, dzb = zs[t + 1] - az;
      float dB = fmaf(dxb, dxb, fmaf(dyb, dyb, dzb * dzb));
      key_insert<K>(a, pack_key_u(dA, (uint)(lo + c0 + t)));
      key_insert<K>(b, pack_key_u(dB, (uint)(lo + c0 + t + 1)));
    }
  }
}

// Pass-D scan over [lo, lo+len): candidates = p1+fl (exact R10 rounding),
// running min only.
__device__ void scan_w(const float* px, const float* py, const float* pz,
                       const float* fx, const float* fy, const float* fz,
                       int lo, int len, float ax, float ay, float az,
                       float& a0, float& b0) {
  #pragma unroll 1
  for (int c0 = 0; c0 < len; c0 += 8) {
    f8 xs, ys, zs, us, vs, ws;
    sload6(px, py, pz, fx, fy, fz, (lo + c0) * 4, xs, ys, zs, us, vs, ws);
    #pragma unroll
    for (int t = 0; t < 8; t += 2) {
      float cxa = xs[t] + us[t], cya = ys[t] + vs[t], cza = zs[t] + ws[t];
      float dxa = cxa - ax, dya = cya - ay, dza = cza - az;
      float dA = fmaf(dxa, dxa, fmaf(dya, dya, dza * dza));
      float cxb = xs[t + 1] + us[t + 1], cyb = ys[t + 1] + vs[t + 1],
            czb = zs[t + 1] + ws[t + 1];
      float dxb = cxb - ax, dyb = cyb - ay, dzb = czb - az;
      float dB = fmaf(dxb, dxb, fmaf(dyb, dyb, dzb * dzb));
      a0 = fminf(a0, dA);
      b0 = fminf(b0, dB);
    }
  }
}

// r in [0,340) -> scale s, batch b, query-group base i0, candidate lo.
// Only i0/lo depend on wv; s,b are block-uniform.
__device__ __forceinline__ void decode(int r, int wv, int& s, int& b,
                                       int& i0, int& lo, int& N, int& cpw,
                                       int& off, float& alpha) {
  int rr;
  if (r < 256)      { s = 0; rr = r; }
  else if (r < 320) { s = 1; rr = r - 256; }
  else if (r < 336) { s = 2; rr = r - 320; }
  else              { s = 3; rr = r - 336; }
  N = 8192 >> s;
  cpw = 8 >> s;
  int perb = 128 >> (2 * s);
  b = rr >> (7 - 2 * s);
  int chunk = rr & (perb - 1);
  int qg = (chunk << s) + (wv >> (3 - s));
  i0 = qg << 6;
  lo = (wv & (cpw - 1)) << 10;
  off = 16384 - (16384 >> s);
  alpha = 0.02f * (float)(1 << s);
}

// Stage per-thread list; group leader (wave with cr==0) merges its
// qgroup's cpw lists. Returns true for leader threads.
template <int K>
__device__ __forceinline__ bool merge_group(float (&a)[K], float* sm,
                                            int tid, int cpw) {
  const int STR = K | 1;   // odd stride: 2-way bank aliasing only (free)
  int q = tid & 63, wv = tid >> 6;
  #pragma unroll
  for (int m = 0; m < K; ++m) sm[(wv * 64 + q) * STR + m] = a[m];
  __syncthreads();
  if (wv & (cpw - 1)) return false;
  for (int w = wv + 1; w < wv + cpw; ++w)
    #pragma unroll
    for (int m = 0; m < K; ++m)
      key_insert<K>(a, sm[(w * 64 + q) * STR + m]);
  return true;
}

// ---------- kernels ----------

__global__ __launch_bounds__(1) void k_zero(Params P) {
  P.out[0] = 0.f;
  P.cnt[0] = 0u;
}

// Persistent blocks; task t: [0,340) A, [340,680) B, [680,1020) C,
// [1020,1500) D-block (64 queries x full N; 8 waves x N/8 cands + LDS
// merge -> exact per-query min -> wave_sum -> one atomicAdd).
__global__ __launch_bounds__(512, 8) void k_work(Params P) {
  __shared__ float sm[8 * 64 * 11];   // 22.5 KB merge staging
  __shared__ uint ts;
  int tid = threadIdx.x, q = tid & 63, wv = tid >> 6;

  uint t = blockIdx.x;                // static first task, no pop burst
  while (t < NTASK) {
    if (t < 1020u) {
      int pass = (int)t / 340, r = (int)t % 340;
      int s, b, i0, lo, N, cpw, off; float alpha;
      decode(r, wv, s, b, i0, lo, N, cpw, off, alpha);
      int i = i0 + q;
      int lo_u = __builtin_amdgcn_readfirstlane(lo);

      if (pass == 0) {            // A: p2 self top-10 -> cv2
        const float* p2 = P.pc2[s] + b * 3 * N;
        float ax = p2[i], ay = p2[N + i], az = p2[2 * N + i];
        float a[10], bb[10];
        #pragma unroll
        for (int m = 0; m < 10; ++m) { a[m] = 3.0e38f; bb[m] = 3.0e38f; }
        scan_k<10>(p2, p2 + N, p2 + 2 * N, lo_u, ax, ay, az, a, bb);
        merge_pair<10>(a, bb);
        if (merge_group<10>(a, sm, tid, cpw)) {
          float sx = 0.f, sy = 0.f, sz = 0.f;
          #pragma unroll
          for (int m = 0; m < 10; ++m) {
            int j = (int)(__float_as_uint(a[m]) & 0x1FFFu);
            sx += p2[j]; sy += p2[N + j]; sz += p2[2 * N + j];
          }
          const float inv9 = 1.f / 9.f;
          P.cv2[b * NTOT + off + i] = make_float4((sx - 10.f * ax) * inv9,
                                                  (sy - 10.f * ay) * inv9,
                                                  (sz - 10.f * az) * inv9,
                                                  0.f);
        }
      } else if (pass == 1) {     // B: p1 self top-10 -> cvw + smooth
        const float* p1 = P.pc1[s] + b * 3 * N;
        const float* fl = P.fl[s] + b * 3 * N;
        float ax = p1[i], ay = p1[N + i], az = p1[2 * N + i];
        float a[10], bb[10];
        #pragma unroll
        for (int m = 0; m < 10; ++m) { a[m] = 3.0e38f; bb[m] = 3.0e38f; }
        scan_k<10>(p1, p1 + N, p1 + 2 * N, lo_u, ax, ay, az, a, bb);
        merge_pair<10>(a, bb);
        if (merge_group<10>(a, sm, tid, cpw)) {
          float fix = fl[i], fiy = fl[N + i], fiz = fl[2 * N + i];
          float wix = ax + fix, wiy = ay + fiy, wiz = az + fiz;
          float sx = 0.f, sy = 0.f, sz = 0.f, smooth = 0.f;
          float dmax = -1.f, worst = 0.f;
          #pragma unroll
          for (int m = 0; m < 10; ++m) {
            int j = (int)(__float_as_uint(a[m]) & 0x1FFFu);
            float px = p1[j], py = p1[N + j], pz = p1[2 * N + j];
            float flx = fl[j], fly = fl[N + j], flz = fl[2 * N + j];
            sx += px + flx; sy += py + fly; sz += pz + flz;
            float ddx = px - ax, ddy = py - ay, ddz = pz - az;
            float d = fmaf(ddx, ddx, fmaf(ddy, ddy, ddz * ddz));  // exact
            float gx = flx - fix, gy = fly - fiy, gz = flz - fiz;
            float term = sqrtf(fmaf(gx, gx, fmaf(gy, gy, gz * gz)));
            smooth += term;
            if (d > dmax) { dmax = d; worst = term; }  // drop farthest (k9)
          }
          smooth -= worst;
          const float inv9 = 1.f / 9.f;
          P.cvw[b * NTOT + off + i] = make_float4((sx - 10.f * wix) * inv9,
                                                  (sy - 10.f * wiy) * inv9,
                                                  (sz - 10.f * wiz) * inv9,
                                                  0.f);
          float ssum = wave_sum(smooth * (1.f / 8.f));
          if (q == 0) atomicAdd(P.out, alpha * 0.5f * ssum);
        }
      } else {                    // C: warp -> p2 top-5 -> packed keys
        const float* p1 = P.pc1[s] + b * 3 * N;
        const float* fl = P.fl[s] + b * 3 * N;
        const float* p2 = P.pc2[s] + b * 3 * N;
        float ax = p1[i] + fl[i], ay = p1[N + i] + fl[N + i],
              az = p1[2 * N + i] + fl[2 * N + i];   // R10-exact query
        float a[5], bb[5];
        #pragma unroll
        for (int m = 0; m < 5; ++m) { a[m] = 3.0e38f; bb[m] = 3.0e38f; }
        scan_k<5>(p2, p2 + N, p2 + 2 * N, lo_u, ax, ay, az, a, bb);
        merge_pair<5>(a, bb);
        if (merge_group<5>(a, sm, tid, cpw)) {
          #pragma unroll
          for (int m = 0; m < 5; ++m)
            P.keys[m * (2 * NTOT) + b * NTOT + off + i] = a[m];
        }
      }
    } else {
      // D-block: 64 queries (p2) x full N warp-candidates; 8 waves split
      // candidates, LDS merge gives the exact per-query min.
      int dt = (int)(t - 1020u);
      int s, tb;
      if (dt < 256)      { s = 0; tb = dt; }        // 2*8192/64
      else if (dt < 384) { s = 1; tb = dt - 256; }  // 2*4096/64
      else if (dt < 448) { s = 2; tb = dt - 384; }  // 2*2048/64
      else               { s = 3; tb = dt - 448; }  // 2*1024/64
      int N = 8192 >> s;
      int qpb = N >> 6;                // query-groups per batch
      int b = tb >= qpb;               // s,b block-uniform (from t only)
      int qg = tb - b * qpb;
      int i = qg * 64 + q;
      int len = N >> 3;                // cands per wave (>=128, /8)
      int lo = wv * len;
      float alpha = 0.02f * (float)(1 << s);
      const float* p1 = P.pc1[s] + b * 3 * N;
      const float* fl = P.fl[s] + b * 3 * N;
      const float* p2 = P.pc2[s] + b * 3 * N;
      float ax = p2[i], ay = p2[N + i], az = p2[2 * N + i];
      float a0 = 3.0e38f, b0 = 3.0e38f;
      int lo_u = __builtin_amdgcn_readfirstlane(lo);
      scan_w(p1, p1 + N, p1 + 2 * N, fl, fl + N, fl + 2 * N,
             lo_u, len, ax, ay, az, a0, b0);
      float a[1];
      a[0] = fminf(a0, b0);
      if (merge_group<1>(a, sm, tid, 8)) {   // leader = wave 0
        float msum = wave_sum(a[0]);
        if (q == 0) atomicAdd(P.out, alpha * 0.5f * msum);
      }
    }
    __syncthreads();              // sm + ts reuse safety
    if (tid == 0) ts = NBLK + atomicAdd(P.cnt, 1u);
    __syncthreads();
    t = ts;
  }
}

// Epilogue: C top-5 -> exact dist1 + inverse-distance cv2 interp ->
// curvature. 30720 threads. Block-level atomic reduction (R18).
__global__ __launch_bounds__(256) void k_epi(Params P) {
  __shared__ float part[4];
  int t = blockIdx.x * 256 + threadIdx.x;   // [0, 2*NTOT)
  int b = t >= NTOT;
  int r = t - b * NTOT;
  int s, i;
  if (r < 8192)       { s = 0; i = r; }
  else if (r < 12288) { s = 1; i = r - 8192; }
  else if (r < 14336) { s = 2; i = r - 12288; }
  else                { s = 3; i = r - 14336; }
  int N = 8192 >> s;
  int off = 16384 - (16384 >> s);
  float alpha = 0.02f * (float)(1 << s);
  const float* p1 = P.pc1[s] + b * 3 * N;
  const float* fl = P.fl[s] + b * 3 * N;
  const float* p2 = P.pc2[s] + b * 3 * N;
  float ax = p1[i] + fl[i], ay = p1[N + i] + fl[N + i],
        az = p1[2 * N + i] + fl[2 * N + i];
  float dist1 = 3.0e38f, wsum = 0.f, ix = 0.f, iy = 0.f, iz = 0.f;
  #pragma unroll
  for (int m = 0; m < 5; ++m) {
    uint key = __float_as_uint(P.keys[m * (2 * NTOT) + b * NTOT + off + i]);
    int j = (int)(key & 0x1FFFu);
    float px = p2[j], py = p2[N + j], pz = p2[2 * N + j];
    float ddx = px - ax, ddy = py - ay, ddz = pz - az;
    float d = fmaf(ddx, ddx, fmaf(ddy, ddy, ddz * ddz));  // exact
    dist1 = fminf(dist1, d);
    float w = 1.f / (d + 1e-8f);
    wsum += w;
    float4 cv = P.cv2[b * NTOT + off + j];
    ix += w * cv.x; iy += w * cv.y; iz += w * cv.z;
  }
  float inv = 1.f / wsum;
  ix *= inv; iy *= inv; iz *= inv;
  float4 cw = P.cvw[b * NTOT + off + i];
  float ex = ix - cw.x, ey = iy - cw.y, ez = iz - cw.z;
  float curv = fmaf(ex, ex, fmaf(ey, ey, ez * ez));
  float csum = wave_sum(alpha * 0.5f * (dist1 + 0.3f * curv));
  int wv = threadIdx.x >> 6;
  if ((threadIdx.x & 63) == 0) part[wv] = csum;
  __syncthreads();
  if (threadIdx.x == 0) {
    float v = 0.f;
    #pragma unroll
    for (int m = 0; m < 4; ++m) v += part[m];
    atomicAdd(P.out, v);        // 120 total
  }
}

extern "C" void kernel_launch(void* const* d_in, const int* in_sizes, int n_in,
                              void* d_out, int out_size, void* d_ws,
                              size_t ws_size, hipStream_t stream) {
  Params P;
  for (int s = 0; s < 4; ++s) {
    P.pc1[s] = (const float*)d_in[s];
    P.pc2[s] = (const float*)d_in[4 + s];
    P.fl[s]  = (const float*)d_in[8 + s];
  }
  char* ws = (char*)d_ws;
  P.cv2  = (float4*)ws;                    // 491520 B
  P.cvw  = (float4*)(ws + 491520);         // 491520 B
  P.keys = (float*)(ws + 983040);          // 614400 B
  P.cnt  = (uint*)(ws + 1597440);          // 64 B
  P.out  = (float*)d_out;

  k_zero<<<dim3(1), dim3(1), 0, stream>>>(P);
  k_work<<<dim3(NBLK), dim3(512), 0, stream>>>(P);
  k_epi<<<dim3(120), dim3(256), 0, stream>>>(P);
}

// Round 14
// 292.449 us; speedup vs baseline: 2.1921x; 1.0387x over previous
//
#include <hip/hip_runtime.h>
#include <math.h>

// PointPWC multi-scale loss. B=2, scales N={8192,4096,2048,1024}.
// Inputs (B,3,N) fp32 channel-major. Output: single fp32 scalar.
//
// R22 = R18 verbatim (best measured: 290.0us total, k_work 239us,
// absmax 0.0). Terminal revert per R20/R21 pre-commitment.
//
// Final state of evidence:
//  - k_work scan (239us): survived 7 structural attacks (LDS bcast,
//    SMEM x8/x16, packed float4 +37%, readlane +58%, 2q/lane +10%,
//    3 queue granularities). ~60% true VALU duty + SMEM broadcast
//    latency partially hidden by 8 waves/SIMD; R14 config is the
//    empirical optimum of this family.
//  - dispatch gap (~50us): launch/boundary mechanics floor. Deleting
//    k_init's work changed it by 2us (R21); grid-barrier fusion costs
//    +350us in per-block L2 writebacks on 8 XCDs (R19); block-level
//    atomic reduction in k_epi recovered 7us (R18, kept).
// Structure: k_init (warp=p1+fl precompute + d2u init), k_work
// (persistent 1024 blocks, A/B/C heavy tasks + 1360 D-micro fillers,
// SMEM x16 broadcast 12B/cand, selection keys bit-identical since R10),
// k_epi (C-epilogue + D-sum, one atomicAdd per block).

#define UNIT 1024
#define NTOT 15360
#define MASKC 0xFFFFE000u
#define NTASK 2380u   // 340 A + 340 B + 340 C + 1360 D-micro

typedef unsigned int uint;
typedef __attribute__((ext_vector_type(16))) float f16v;

struct Params {
  const float* pc1[4];
  const float* pc2[4];
  const float* fl[4];
  float4* cv2;   // [B][NTOT]
  float4* cvw;   // [B][NTOT]
  float* keys;   // [5][B*NTOT] packed top-5 keys (pass C)
  uint* d2u;     // [B*NTOT] partial mins (pass D)
  uint* cnt;     // task queue counter
  float* warp;   // per-scale [B][3][N] warped p1 (= p1+fl)
  float* out;
};

// ---------- helpers ----------

__device__ __forceinline__ float wave_sum(float v) {
  #pragma unroll
  for (int o = 32; o; o >>= 1) v += __shfl_down(v, o, 64);
  return v;
}

template <int K>
__device__ __forceinline__ void key_insert(float (&kd)[K], float kf) {
  #pragma unroll
  for (int m = K - 1; m >= 1; --m)
    kd[m] = __builtin_amdgcn_fmed3f(kf, kd[m - 1], kd[m]);
  kd[0] = fminf(kd[0], kf);
}

template <int K>
__device__ __forceinline__ void merge_pair(float (&a)[K], const float (&b)[K]) {
  #pragma unroll
  for (int m = 0; m < K; ++m) key_insert<K>(a, b[m]);
}

__device__ __forceinline__ float pack_key_u(float d, uint iw) {
  return __uint_as_float((__float_as_uint(d) & MASKC) | iw);
}

// Wave-uniform broadcast of 16 candidates (3 planes, 12B/cand) into
// SGPRs. Loads + waitcnt fused in ONE asm block (SMEM completes
// out-of-order; only lgkmcnt(0) is safe; split issue/wait risks copies
// of in-flight regs). Pointers must be block-uniform for "s" to hold.
__device__ __forceinline__ void sload3x16(const float* px, const float* py,
                                          const float* pz, int boff,
                                          f16v& x, f16v& y, f16v& z) {
  asm volatile(
      "s_load_dwordx16 %0, %3, %6\n\t"
      "s_load_dwordx16 %1, %4, %6\n\t"
      "s_load_dwordx16 %2, %5, %6\n\t"
      "s_waitcnt lgkmcnt(0)"
      : "=&s"(x), "=&s"(y), "=&s"(z)
      : "s"(px), "s"(py), "s"(pz), "s"(boff));
}

// Top-K scan over [lo, lo+UNIT); candidates from SGPRs. Two chains.
template <int K>
__device__ void scan_k(const float* px, const float* py, const float* pz,
                       int lo, float ax, float ay, float az,
                       float (&a)[K], float (&b)[K]) {
  #pragma unroll 1
  for (int c0 = 0; c0 < UNIT; c0 += 16) {
    f16v xs, ys, zs;
    sload3x16(px, py, pz, (lo + c0) * 4, xs, ys, zs);
    #pragma unroll
    for (int t = 0; t < 16; t += 2) {
      float dxa = xs[t] - ax, dya = ys[t] - ay, dza = zs[t] - az;
      float dA = fmaf(dxa, dxa, fmaf(dya, dya, dza * dza));
      float dxb = xs[t + 1] - ax, dyb = ys[t + 1] - ay, dzb = zs[t + 1] - az;
      float dB = fmaf(dxb, dxb, fmaf(dyb, dyb, dzb * dzb));
      key_insert<K>(a, pack_key_u(dA, (uint)(lo + c0 + t)));
      key_insert<K>(b, pack_key_u(dB, (uint)(lo + c0 + t + 1)));
    }
  }
}

// Min-only scan over [lo, lo+len): candidates from SGPRs (pass D uses
// precomputed warp -> 7 VALU/candidate).
__device__ void scan_m(const float* px, const float* py, const float* pz,
                       int lo, int len, float ax, float ay, float az,
                       float& a0, float& b0) {
  #pragma unroll 1
  for (int c0 = 0; c0 < len; c0 += 16) {
    f16v xs, ys, zs;
    sload3x16(px, py, pz, (lo + c0) * 4, xs, ys, zs);
    #pragma unroll
    for (int t = 0; t < 16; t += 2) {
      float dxa = xs[t] - ax, dya = ys[t] - ay, dza = zs[t] - az;
      float dA = fmaf(dxa, dxa, fmaf(dya, dya, dza * dza));
      float dxb = xs[t + 1] - ax, dyb = ys[t + 1] - ay, dzb = zs[t + 1] - az;
      float dB = fmaf(dxb, dxb, fmaf(dyb, dyb, dzb * dzb));
      a0 = fminf(a0, dA);
      b0 = fminf(b0, dB);
    }
  }
}

// r in [0,340) -> scale s, batch b, query-group base i0, candidate lo.
// Only i0/lo depend on wv; s,b are block-uniform.
__device__ __forceinline__ void decode(int r, int wv, int& s, int& b,
                                       int& i0, int& lo, int& N, int& cpw,
                                       int& off, float& alpha) {
  int rr;
  if (r < 256)      { s = 0; rr = r; }
  else if (r < 320) { s = 1; rr = r - 256; }
  else if (r < 336) { s = 2; rr = r - 320; }
  else              { s = 3; rr = r - 336; }
  N = 8192 >> s;
  cpw = 8 >> s;
  int perb = 128 >> (2 * s);
  b = rr >> (7 - 2 * s);
  int chunk = rr & (perb - 1);
  int qg = (chunk << s) + (wv >> (3 - s));
  i0 = qg << 6;
  lo = (wv & (cpw - 1)) << 10;
  off = 16384 - (16384 >> s);
  alpha = 0.02f * (float)(1 << s);
}

// Stage per-thread list; group leader (wave with cr==0) merges its
// qgroup's cpw lists. Returns true for leader threads.
template <int K>
__device__ __forceinline__ bool merge_group(float (&a)[K], float* sm,
                                            int tid, int cpw) {
  const int STR = K | 1;   // odd stride: 2-way bank aliasing only (free)
  int q = tid & 63, wv = tid >> 6;
  #pragma unroll
  for (int m = 0; m < K; ++m) sm[(wv * 64 + q) * STR + m] = a[m];
  __syncthreads();
  if (wv & (cpw - 1)) return false;
  for (int w = wv + 1; w < wv + cpw; ++w)
    #pragma unroll
    for (int m = 0; m < K; ++m)
      key_insert<K>(a, sm[(w * 64 + q) * STR + m]);
  return true;
}

// ---------- kernels ----------

// Init scalars/d2u AND precompute warp = p1+fl (flat per scale; same
// rounding as the p1[j]+fl[j] it replaces -> bit-identical).
__global__ __launch_bounds__(256) void k_init(Params P) {
  int t = blockIdx.x * 256 + threadIdx.x;
  if (t == 0) { P.out[0] = 0.f; *P.cnt = 1024u; }   // first tasks static
  if (t < 2 * NTOT) P.d2u[t] = 0x7F7FFFFFu;         // FLT_MAX bits
  int s, r;
  if (t < 49152)      { s = 0; r = t; }
  else if (t < 73728) { s = 1; r = t - 49152; }
  else if (t < 86016) { s = 2; r = t - 73728; }
  else if (t < 92160) { s = 3; r = t - 86016; }
  else return;
  int base6 = (s == 0) ? 0 : (s == 1) ? 49152 : (s == 2) ? 73728 : 86016;
  P.warp[base6 + r] = P.pc1[s][r] + P.fl[s][r];
}

// Persistent blocks; task t: [0,340) A, [340,680) B, [680,1020) C,
// [1020,2380) D-micro ((s,b) from t ONLY -> SGPR-uniform base pointers;
// 8 waves split within-batch wave-units u = ti*8 + wv).
__global__ __launch_bounds__(512, 8) void k_work(Params P) {
  __shared__ float sm[8 * 64 * 11];   // 22.5 KB merge staging
  __shared__ uint ts;
  int tid = threadIdx.x, q = tid & 63, wv = tid >> 6;

  uint t = blockIdx.x;                // static first task, no pop burst
  while (t < NTASK) {
    if (t < 1020u) {
      int pass = (int)t / 340, r = (int)t % 340;
      int s, b, i0, lo, N, cpw, off; float alpha;
      decode(r, wv, s, b, i0, lo, N, cpw, off, alpha);
      int i = i0 + q;
      int lo_u = __builtin_amdgcn_readfirstlane(lo);

      if (pass == 0) {            // A: p2 self top-10 -> cv2
        const float* p2 = P.pc2[s] + b * 3 * N;
        float ax = p2[i], ay = p2[N + i], az = p2[2 * N + i];
        float a[10], bb[10];
        #pragma unroll
        for (int m = 0; m < 10; ++m) { a[m] = 3.0e38f; bb[m] = 3.0e38f; }
        scan_k<10>(p2, p2 + N, p2 + 2 * N, lo_u, ax, ay, az, a, bb);
        merge_pair<10>(a, bb);
        if (merge_group<10>(a, sm, tid, cpw)) {
          float sx = 0.f, sy = 0.f, sz = 0.f;
          #pragma unroll
          for (int m = 0; m < 10; ++m) {
            int j = (int)(__float_as_uint(a[m]) & 0x1FFFu);
            sx += p2[j]; sy += p2[N + j]; sz += p2[2 * N + j];
          }
          const float inv9 = 1.f / 9.f;
          P.cv2[b * NTOT + off + i] = make_float4((sx - 10.f * ax) * inv9,
                                                  (sy - 10.f * ay) * inv9,
                                                  (sz - 10.f * az) * inv9,
                                                  0.f);
        }
      } else if (pass == 1) {     // B: p1 self top-10 -> cvw + smooth
        const float* p1 = P.pc1[s] + b * 3 * N;
        const float* fl = P.fl[s] + b * 3 * N;
        float ax = p1[i], ay = p1[N + i], az = p1[2 * N + i];
        float a[10], bb[10];
        #pragma unroll
        for (int m = 0; m < 10; ++m) { a[m] = 3.0e38f; bb[m] = 3.0e38f; }
        scan_k<10>(p1, p1 + N, p1 + 2 * N, lo_u, ax, ay, az, a, bb);
        merge_pair<10>(a, bb);
        if (merge_group<10>(a, sm, tid, cpw)) {
          float fix = fl[i], fiy = fl[N + i], fiz = fl[2 * N + i];
          float wix = ax + fix, wiy = ay + fiy, wiz = az + fiz;
          float sx = 0.f, sy = 0.f, sz = 0.f, smooth = 0.f;
          float dmax = -1.f, worst = 0.f;
          #pragma unroll
          for (int m = 0; m < 10; ++m) {
            int j = (int)(__float_as_uint(a[m]) & 0x1FFFu);
            float px = p1[j], py = p1[N + j], pz = p1[2 * N + j];
            float flx = fl[j], fly = fl[N + j], flz = fl[2 * N + j];
            sx += px + flx; sy += py + fly; sz += pz + flz;
            float ddx = px - ax, ddy = py - ay, ddz = pz - az;
            float d = fmaf(ddx, ddx, fmaf(ddy, ddy, ddz * ddz));  // exact
            float gx = flx - fix, gy = fly - fiy, gz = flz - fiz;
            float term = sqrtf(fmaf(gx, gx, fmaf(gy, gy, gz * gz)));
            smooth += term;
            if (d > dmax) { dmax = d; worst = term; }  // drop farthest (k9)
          }
          smooth -= worst;
          const float inv9 = 1.f / 9.f;
          P.cvw[b * NTOT + off + i] = make_float4((sx - 10.f * wix) * inv9,
                                                  (sy - 10.f * wiy) * inv9,
                                                  (sz - 10.f * wiz) * inv9,
                                                  0.f);
          float ssum = wave_sum(smooth * (1.f / 8.f));
          if (q == 0) atomicAdd(P.out, alpha * 0.5f * ssum);
        }
      } else {                    // C: warp -> p2 top-5 -> packed keys
        int base6 = (s == 0) ? 0 : (s == 1) ? 49152 : (s == 2) ? 73728
                                                               : 86016;
        const float* wq = P.warp + base6 + b * 3 * N;
        const float* p2 = P.pc2[s] + b * 3 * N;
        float ax = wq[i], ay = wq[N + i], az = wq[2 * N + i];  // == p1+fl
        float a[5], bb[5];
        #pragma unroll
        for (int m = 0; m < 5; ++m) { a[m] = 3.0e38f; bb[m] = 3.0e38f; }
        scan_k<5>(p2, p2 + N, p2 + 2 * N, lo_u, ax, ay, az, a, bb);
        merge_pair<5>(a, bb);
        if (merge_group<5>(a, sm, tid, cpw)) {
          #pragma unroll
          for (int m = 0; m < 5; ++m)
            P.keys[m * (2 * NTOT) + b * NTOT + off + i] = a[m];
        }
      }
    } else {                      // D-micro: p2 -> warp min, atomicMin
      int dm = (int)(t - 1020u);
      int s, tb;
      if (dm < 1024)      { s = 0; tb = dm; }
      else if (dm < 1280) { s = 1; tb = dm - 1024; }
      else if (dm < 1344) { s = 2; tb = dm - 1280; }
      else                { s = 3; tb = dm - 1344; }
      int N = 8192 >> s;
      int tpb = 512 >> (2 * s);            // tasks per batch
      int b = tb >> (9 - 2 * s);
      int ti = tb & (tpb - 1);
      int u = ti * 8 + wv;                 // wave-unit within batch
      int rpq = 32 >> s;                   // 256-ranges per qgroup
      int qg = u >> (5 - s);
      int rg = u & (rpq - 1);
      int i = qg * 64 + q, lo = rg * 256;
      int off = 16384 - (16384 >> s);
      int base6 = (s == 0) ? 0 : (s == 1) ? 49152 : (s == 2) ? 73728
                                                             : 86016;
      const float* wc = P.warp + base6 + b * 3 * N;  // block-uniform
      const float* p2 = P.pc2[s] + b * 3 * N;
      float ax = p2[i], ay = p2[N + i], az = p2[2 * N + i];
      float a0 = 3.0e38f, b0 = 3.0e38f;
      int lo_u = __builtin_amdgcn_readfirstlane(lo);
      scan_m(wc, wc + N, wc + 2 * N, lo_u, 256, ax, ay, az, a0, b0);
      atomicMin(P.d2u + b * NTOT + off + i, __float_as_uint(fminf(a0, b0)));
    }
    __syncthreads();              // sm + ts reuse safety
    if (tid == 0) ts = atomicAdd(P.cnt, 1u);
    __syncthreads();
    t = ts;
  }
}

// Epilogue: C top-5 -> exact dist1 + inverse-distance cv2 interp ->
// curvature; plus D partial-min sum. 30720 threads.
// Per-wave partials -> LDS -> ONE atomicAdd per block (120 total).
__global__ __launch_bounds__(256) void k_epi(Params P) {
  __shared__ float part[8];
  int t = blockIdx.x * 256 + threadIdx.x;   // [0, 2*NTOT)
  int b = t >= NTOT;
  int r = t - b * NTOT;
  int s, i;
  if (r < 8192)       { s = 0; i = r; }
  else if (r < 12288) { s = 1; i = r - 8192; }
  else if (r < 14336) { s = 2; i = r - 12288; }
  else                { s = 3; i = r - 14336; }
  int N = 8192 >> s;
  int off = 16384 - (16384 >> s);
  float alpha = 0.02f * (float)(1 << s);
  const float* p1 = P.pc1[s] + b * 3 * N;
  const float* fl = P.fl[s] + b * 3 * N;
  const float* p2 = P.pc2[s] + b * 3 * N;
  float ax = p1[i] + fl[i], ay = p1[N + i] + fl[N + i],
        az = p1[2 * N + i] + fl[2 * N + i];
  float dist1 = 3.0e38f, wsum = 0.f, ix = 0.f, iy = 0.f, iz = 0.f;
  #pragma unroll
  for (int m = 0; m < 5; ++m) {
    uint key = __float_as_uint(P.keys[m * (2 * NTOT) + b * NTOT + off + i]);
    int j = (int)(key & 0x1FFFu);
    float px = p2[j], py = p2[N + j], pz = p2[2 * N + j];
    float ddx = px - ax, ddy = py - ay, ddz = pz - az;
    float d = fmaf(ddx, ddx, fmaf(ddy, ddy, ddz * ddz));  // exact
    dist1 = fminf(dist1, d);
    float w = 1.f / (d + 1e-8f);
    wsum += w;
    float4 cv = P.cv2[b * NTOT + off + j];
    ix += w * cv.x; iy += w * cv.y; iz += w * cv.z;
  }
  float inv = 1.f / wsum;
  ix *= inv; iy *= inv; iz *= inv;
  float4 cw = P.cvw[b * NTOT + off + i];
  float ex = ix - cw.x, ey = iy - cw.y, ez = iz - cw.z;
  float curv = fmaf(ex, ex, fmaf(ey, ey, ez * ez));
  float csum = wave_sum(dist1 + 0.3f * curv);
  float msum = wave_sum(__uint_as_float(P.d2u[t]));
  int wv = threadIdx.x >> 6;
  if ((threadIdx.x & 63) == 0) {
    part[wv] = alpha * 0.5f * csum;       // alpha is wave-uniform
    part[4 + wv] = alpha * 0.5f * msum;
  }
  __syncthreads();
  if (threadIdx.x == 0) {
    float v = 0.f;
    #pragma unroll
    for (int m = 0; m < 8; ++m) v += part[m];
    atomicAdd(P.out, v);
  }
}

extern "C" void kernel_launch(void* const* d_in, const int* in_sizes, int n_in,
                              void* d_out, int out_size, void* d_ws,
                              size_t ws_size, hipStream_t stream) {
  Params P;
  for (int s = 0; s < 4; ++s) {
    P.pc1[s] = (const float*)d_in[s];
    P.pc2[s] = (const float*)d_in[4 + s];
    P.fl[s]  = (const float*)d_in[8 + s];
  }
  char* ws = (char*)d_ws;
  P.cv2  = (float4*)ws;                    // 491520 B
  P.cvw  = (float4*)(ws + 491520);         // 491520 B
  P.keys = (float*)(ws + 983040);          // 614400 B
  P.d2u  = (uint*)(ws + 1597440);          // 122880 B
  P.cnt  = (uint*)(ws + 1720320);          // 64 B
  P.warp = (float*)(ws + 1720384);         // 368640 B (total 2089024)
  P.out  = (float*)d_out;

  k_init<<<dim3(360), dim3(256), 0, stream>>>(P);
  k_work<<<dim3(1024), dim3(512), 0, stream>>>(P);
  k_epi<<<dim3(120), dim3(256), 0, stream>>>(P);
}